// Round 13
// baseline (356.648 us; speedup 1.0000x reference)
//
#include <hip/hip_runtime.h>

// EntityAwareLSTMLayer: B=1024, T=365, DYN=32, STATIC=27, U=256 (3U=768)
// Round 17: micro-cuts on the R16 base (316us). Verified floors: A-reads
//   minimal (4/wave), M-waste locked (B/CUs), 1 barrier/step minimal.
//   Remaining fat ~10% (phase-sum floor ~283us):
//   1) adjacent-unit pairing: lane owns units {u, u+1} (B-frag n = wv*32
//      + 2*mm + h) -> ONE ds_write_b16 per lane (was 2x ds_write_b8);
//      paired bytes share a dword -> uniform 2-way banks (free). Out-store
//      becomes one float2.
//   2) split-K MI chains: (a0->a1) + (a2->a3), scalar add of element 0.
//      Chain depth 4L -> 2L+4; costs 6 int adds/lane/step.
//   3) s_setprio(1) around the MI block (T5: per-wave role diversity
//      exists mid-step: one wave in MI while the other tails).
//   Everything else = R16 (i8 W_hh, 4-timestep x windows, rcp tail,
//   grouped A-rows, 2 waves/SIMD, 1 barrier/step).

typedef short short8 __attribute__((ext_vector_type(8)));
typedef short short4s __attribute__((ext_vector_type(4)));
typedef float f32x4 __attribute__((ext_vector_type(4)));
typedef int   i32x4 __attribute__((ext_vector_type(4)));

#define T_STEPS 365
#define UNITS   256
#define G3      768
#define MROWS   4
#define NWGS    256
#define HP8     288   // A row stride in BYTES (i8); 72 dw == 8 mod 32 -> 2-way free
#define XROW    (T_STEPS * 32)   // 11,680 shorts per batch row
#define XPAD    96               // covers window-91 overread (steps 365..367)
#define WP8_BYTES (256 * G3)     // 196,608: i8 W_hh residual frags

__device__ __forceinline__ unsigned short f2bf(float x) {
    union { float f; unsigned u; } v; v.f = x;
    return (unsigned short)((v.u + 0x7FFFu + ((v.u >> 16) & 1u)) >> 16);
}
__device__ __forceinline__ float rcp_(float x) {
    float r; asm("v_rcp_f32 %0, %1" : "=v"(r) : "v"(x)); return r;
}
__device__ __forceinline__ float sigm_(float x) {      // rcp(1+e^-x); rcp(inf)=0
    return rcp_(1.0f + __expf(-x));
}
__device__ __forceinline__ float tanh_(float x) {      // 1-2*rcp(1+e^2x)
    return 1.0f - 2.0f * rcp_(1.0f + __expf(2.0f * x));
}
__device__ __forceinline__ f32x4 MF(short8 a, short8 b, f32x4 c) {
    return __builtin_amdgcn_mfma_f32_16x16x32_bf16(a, b, c, 0, 0, 0);
}
__device__ __forceinline__ i32x4 MI(i32x4 a, i32x4 b, i32x4 c) {
    return __builtin_amdgcn_mfma_i32_16x16x64_i8(a, b, c, 0, 0, 0);
}

// Pack weights (identical to R12..R16, validated):
//  - W_hh residual (k<256) -> i8 frags: (k,n) at wp8[((k>>6)*768+n)*64+(k&63)],
//    value rint(v*1024) clamped to +-127.
//  - W_ih -> bf16 frags: (kx,n) at wpx[((kx>>3)*768+n)*8+(kx&7)]
__global__ __launch_bounds__(256) void pack_weights(
    const float* __restrict__ w_ih, const float* __restrict__ w_hh,
    signed char* __restrict__ wp8, unsigned short* __restrict__ wpx)
{
    int idx = blockIdx.x * 256 + threadIdx.x;
    if (idx < 256 * G3) {
        const int k = idx / G3, n = idx - k * G3;
        float v = w_hh[k * G3 + n];
        if ((n & 255) == k) v -= 1.0f;   // subtract eye3 tile (identity exact in fp32)
        int q = (int)rintf(v * 1024.0f);
        q = q > 127 ? 127 : (q < -127 ? -127 : q);
        wp8[((size_t)((k >> 6) * G3) + n) * 64 + (k & 63)] = (signed char)q;
    } else if (idx < (256 + 32) * G3) {
        const int idx2 = idx - 256 * G3;
        const int kx = idx2 / G3, n = idx2 - kx * G3;
        wpx[((size_t)((kx >> 3) * G3) + n) * 8 + (kx & 7)] = f2bf(w_ih[kx * G3 + n]);
    }
}

// One timestep at window-offset E (compile-time 0..3). FC = this window's
// x-accs (element E = this step); FN = next window's accs, computed when DOX.
#define STEP_BODY(E, FC, FN, DOX, LOADX, W) do {                              \
    const int p_ = (E) & 1;                                                   \
    __syncthreads();                                                          \
    const signed char* Ap_ = &A_s[p_][0][0];                                  \
    const i32x4 a0_ = *(const i32x4*)(Ap_ + abase);                           \
    const i32x4 a1_ = *(const i32x4*)(Ap_ + abase + 64);                      \
    const i32x4 a2_ = *(const i32x4*)(Ap_ + abase + 128);                     \
    const i32x4 a3_ = *(const i32x4*)(Ap_ + abase + 192);                     \
    __builtin_amdgcn_s_setprio(1);                                            \
    /* split-K: two 2-deep chains per acc; h0 chains first */                 \
    i32x4 ifA0_ = MI(a1_, bwi[1][0][0], MI(a0_, bwi[0][0][0], IZERO));        \
    i32x4 ioA0_ = MI(a1_, bwi[1][1][0], MI(a0_, bwi[0][1][0], IZERO));        \
    i32x4 igA0_ = MI(a1_, bwi[1][2][0], MI(a0_, bwi[0][2][0], IZERO));        \
    i32x4 ifB0_ = MI(a3_, bwi[3][0][0], MI(a2_, bwi[2][0][0], IZERO));        \
    i32x4 ioB0_ = MI(a3_, bwi[3][1][0], MI(a2_, bwi[2][1][0], IZERO));        \
    i32x4 igB0_ = MI(a3_, bwi[3][2][0], MI(a2_, bwi[2][2][0], IZERO));        \
    i32x4 ifA1_ = MI(a1_, bwi[1][0][1], MI(a0_, bwi[0][0][1], IZERO));        \
    i32x4 ioA1_ = MI(a1_, bwi[1][1][1], MI(a0_, bwi[0][1][1], IZERO));        \
    i32x4 igA1_ = MI(a1_, bwi[1][2][1], MI(a0_, bwi[0][2][1], IZERO));        \
    i32x4 ifB1_ = MI(a3_, bwi[3][0][1], MI(a2_, bwi[2][0][1], IZERO));        \
    i32x4 ioB1_ = MI(a3_, bwi[3][1][1], MI(a2_, bwi[2][1][1], IZERO));        \
    i32x4 igB1_ = MI(a3_, bwi[3][2][1], MI(a2_, bwi[2][2][1], IZERO));        \
    if (DOX) {                                                                \
        /* next window's x-GEMM: 4 timesteps in M-dim */                      \
        const short8 xu_ = xa;                                                \
        FN[0] = MF(xu_, bwx[0][0], FZERO);                                    \
        FN[1] = MF(xu_, bwx[1][0], FZERO);                                    \
        FN[2] = MF(xu_, bwx[2][0], FZERO);                                    \
        FN[3] = MF(xu_, bwx[0][1], FZERO);                                    \
        FN[4] = MF(xu_, bwx[1][1], FZERO);                                    \
        FN[5] = MF(xu_, bwx[2][1], FZERO);                                    \
        if (LOADX)                                                            \
            xa = *(const short8*)(xq + (size_t)((W) + 2) * 128);              \
    }                                                                         \
    __builtin_amdgcn_s_setprio(0);                                            \
    int q0_, q1_;                                                             \
    {   /* tail h=0: x-part element E, i8-part element 0 */                   \
        const float bh_ = hp[0];                                              \
        const float gf_ = FC[0][E] + bfv[0] + bh_                             \
                        + (float)(ifA0_[0] + ifB0_[0]) * SCL;                 \
        const float go_ = FC[1][E] + bov[0] + bh_                             \
                        + (float)(ioA0_[0] + ioB0_[0]) * SCL;                 \
        const float gg_ = FC[2][E] + bgv[0] + bh_                             \
                        + (float)(igA0_[0] + igB0_[0]) * SCL;                 \
        const float f_  = sigm_(gf_);                                         \
        const float o_  = sigm_(go_);                                         \
        const float gt_ = tanh_(gg_);                                         \
        const float cn_ = f_ * cc[0] + ig[0] * gt_;                           \
        cc[0] = cn_;                                                          \
        const float hn_ = o_ * tanh_(cn_);                                    \
        hp[0] = hn_;                                                          \
        q0_ = __float2int_rn(hn_ * 127.0f);                                   \
    }                                                                         \
    {   /* tail h=1 */                                                        \
        const float bh_ = hp[1];                                              \
        const float gf_ = FC[3][E] + bfv[1] + bh_                             \
                        + (float)(ifA1_[0] + ifB1_[0]) * SCL;                 \
        const float go_ = FC[4][E] + bov[1] + bh_                             \
                        + (float)(ioA1_[0] + ioB1_[0]) * SCL;                 \
        const float gg_ = FC[5][E] + bgv[1] + bh_                             \
                        + (float)(igA1_[0] + igB1_[0]) * SCL;                 \
        const float f_  = sigm_(gf_);                                         \
        const float o_  = sigm_(go_);                                         \
        const float gt_ = tanh_(gg_);                                         \
        const float cn_ = f_ * cc[1] + ig[1] * gt_;                           \
        cc[1] = cn_;                                                          \
        const float hn_ = o_ * tanh_(cn_);                                    \
        hp[1] = hn_;                                                          \
        q1_ = __float2int_rn(hn_ * 127.0f);                                   \
    }                                                                         \
    /* paired write: units u0,u0+1 = 2 adjacent bytes = one b16 */            \
    *(unsigned short*)&A_s[p_ ^ 1][qq][u0] =                                  \
        (unsigned short)((q0_ & 0xFF) | ((q1_ & 0xFF) << 8));                 \
} while (0)

// 4-step window W: steps 4W..4W+3, x-accs FC; E=1 computes FN.
#define WINDOW4(W, FC, FN, LOADX) do {                                        \
    STEP_BODY(0, FC, FN, false, false, W);                                    \
    STEP_BODY(1, FC, FN, true,  LOADX, W);                                    \
    STEP_BODY(2, FC, FN, false, false, W);                                    \
    STEP_BODY(3, FC, FN, false, false, W);                                    \
} while (0)

__global__ __launch_bounds__(512, 2) void lstm_mfma(
    const float* __restrict__ x_dyn,   // [1024][365][32]
    const float* __restrict__ x_sta,   // [1024][27]
    const signed char* __restrict__ wp8,    // i8 W_hh residual frags
    const unsigned short* __restrict__ wpx, // bf16 W_ih frags
    const float* __restrict__ w_sh,    // [27][256]
    const float* __restrict__ bias,    // [768]
    const float* __restrict__ bias_s,  // [256]
    float* __restrict__ out)           // [1024][256]
{
    __shared__ signed char A_s[2][MROWS][HP8];         // 2,304 B (h as i8, dbuf)
    __shared__ unsigned short xs[MROWS * XROW + XPAD]; // 93,632 B (all x, bf16)

    const int tid  = threadIdx.x;
    const int b0   = blockIdx.x * MROWS;
    const int lane = tid & 63;
    const int wv   = tid >> 6;          // wave 0..7, owns units wv*32..+31
    const int mm   = lane & 15;
    const int qq   = lane >> 4;

    // ---- W_hh residual frags resident (adjacent-unit pairing):
    //      lane col n = wv*32 + 2*mm + h  (h = 0,1) ----
    i32x4 bwi[4][3][2];
    #pragma unroll
    for (int ks = 0; ks < 4; ++ks)
        #pragma unroll
        for (int g = 0; g < 3; ++g)
            #pragma unroll
            for (int h = 0; h < 2; ++h) {
                const int n = g * UNITS + wv * 32 + 2 * mm + h;
                bwi[ks][g][h] = *(const i32x4*)(wp8 +
                    ((size_t)(ks * G3) + n) * 64 + qq * 16);
            }
    short8 bwx[3][2];
    #pragma unroll
    for (int g = 0; g < 3; ++g)
        #pragma unroll
        for (int h = 0; h < 2; ++h)
            bwx[g][h] = *(const short8*)(wpx +
                ((size_t)(qq * G3) + g * UNITS + wv * 32 + 2 * mm + h) * 8);

    // ---- pre-stage ALL x for this WG's 4 batch rows (fp32 -> bf16) ----
    #pragma unroll
    for (int r = 0; r < MROWS; ++r) {
        const float4* src = (const float4*)(x_dyn + (size_t)(b0 + r) * XROW);
        short4s* dst = (short4s*)(xs + r * XROW);
        for (int i = tid; i < XROW / 4; i += 512) {
            const float4 v = src[i];
            short4s w;
            w.x = (short)f2bf(v.x); w.y = (short)f2bf(v.y);
            w.z = (short)f2bf(v.z); w.w = (short)f2bf(v.w);
            dst[i] = w;
        }
    }
    // zero the pad (window-91 overread) and both h buffers
    if (tid < XPAD / 2) ((int*)(xs + MROWS * XROW))[tid] = 0;
    {
        int* az = (int*)A_s;
        for (int i = tid; i < 2 * MROWS * HP8 / 4; i += 512) az[i] = 0;
    }
    __syncthreads();

    // ---- cell mapping: lane (mm,qq) owns cells (batch qq, units u0,u0+1) ----
    const int u0 = wv * 32 + 2 * mm;

    const float bfv[2] = { bias[u0],             bias[u0 + 1] };
    const float bov[2] = { bias[UNITS + u0],     bias[UNITS + u0 + 1] };
    const float bgv[2] = { bias[2 * UNITS + u0], bias[2 * UNITS + u0 + 1] };

    float ig[2], cc[2], hp[2];
    #pragma unroll
    for (int h = 0; h < 2; ++h) {
        const int u = u0 + h;
        float s = bias_s[u];
        #pragma unroll
        for (int j = 0; j < 27; ++j)
            s += x_sta[(b0 + qq) * 27 + j] * w_sh[j * UNITS + u];
        ig[h] = sigm_(s);
        cc[h] = 0.0f; hp[h] = 0.0f;
    }

    const int abase = (mm >> 2) * HP8 + qq * 16;        // grouped h A-read
    // x A-frag source: row (batch mm>>2, timestep t0+(mm&3)), k-slice qq*8
    const unsigned short* xq = xs + (size_t)(mm >> 2) * XROW + (mm & 3) * 32 + qq * 8;
    const float SCL = 1.0f / (127.0f * 1024.0f);
    const f32x4 FZERO = {0.f, 0.f, 0.f, 0.f};
    const i32x4 IZERO = {0, 0, 0, 0};

    // ---- prologue: window 0 accs into FA; prefetch window-1 x A-frag ----
    f32x4 FA[6], FB[6];
    short8 xa;
    {
        const short8 x0 = *(const short8*)(xq);
        FA[0] = MF(x0, bwx[0][0], FZERO);
        FA[1] = MF(x0, bwx[1][0], FZERO);
        FA[2] = MF(x0, bwx[2][0], FZERO);
        FA[3] = MF(x0, bwx[0][1], FZERO);
        FA[4] = MF(x0, bwx[1][1], FZERO);
        FA[5] = MF(x0, bwx[2][1], FZERO);
        xa = *(const short8*)(xq + 128);   // window 1
    }

    // windows 0..89 in ping-pong pairs, window 90, then final step 364
    for (int wp = 0; wp < 45; ++wp) {
        const int w0 = wp * 2;
        WINDOW4(w0,     FA, FB, true);
        WINDOW4(w0 + 1, FB, FA, true);
    }
    WINDOW4(90, FA, FB, false);            // computes FB for window 91 (step 364)
    STEP_BODY(0, FB, FA, false, false, 91);

    // paired out-store: units u0, u0+1 are adjacent floats
    {
        float2 o2; o2.x = hp[0]; o2.y = hp[1];
        *(float2*)(out + (size_t)(b0 + qq) * UNITS + u0) = o2;
    }
}

extern "C" void kernel_launch(void* const* d_in, const int* in_sizes, int n_in,
                              void* d_out, int out_size, void* d_ws, size_t ws_size,
                              hipStream_t stream) {
    const float* x_dyn  = (const float*)d_in[0];
    const float* x_sta  = (const float*)d_in[1];
    const float* w_ih   = (const float*)d_in[2];
    const float* w_hh   = (const float*)d_in[3];
    const float* w_sh   = (const float*)d_in[4];
    const float* bias   = (const float*)d_in[5];
    const float* bias_s = (const float*)d_in[6];
    float* out = (float*)d_out;
    signed char* wp8 = (signed char*)d_ws;                            // 196,608 B
    unsigned short* wpx = (unsigned short*)((char*)d_ws + WP8_BYTES); //  49,152 B

    pack_weights<<<((256 + 32) * G3 + 255) / 256, 256, 0, stream>>>(w_ih, w_hh, wp8, wpx);
    lstm_mfma<<<NWGS, 512, 0, stream>>>(x_dyn, x_sta, wp8, wpx, w_sh, bias, bias_s, out);
}

// Round 14
// 350.962 us; speedup vs baseline: 1.0162x; 1.0162x over previous
//
#include <hip/hip_runtime.h>

// EntityAwareLSTMLayer: B=1024, T=365, DYN=32, STATIC=27, U=256 (3U=768)
// Round 18: REVERT to R16 (measured best: 316-318us). R17's micro-bundle
//   (setprio + split-K + write-pairing) was net -3%: extra VALU ops and
//   scheduler interference outweighed ~25cy/step of saved LDS writes.
//   R16 structure (all components individually validated):
//   - i8 W_hh residual via mfma_i32_16x16x64_i8, all frags register-resident.
//   - 4-timestep x windows in the MFMA M-dim (6 bf16 MFMAs per 4 steps).
//   - grouped h A-rows (arow=mm>>2): acc elements identical -> no selects.
//   - v_rcp-based sigmoid/tanh tail; bias+identity added in tail.
//   - 8 waves x 32 units, 2 waves/SIMD, x pre-staged in LDS, 1 barrier/step.

typedef short short8 __attribute__((ext_vector_type(8)));
typedef short short4s __attribute__((ext_vector_type(4)));
typedef float f32x4 __attribute__((ext_vector_type(4)));
typedef int   i32x4 __attribute__((ext_vector_type(4)));

#define T_STEPS 365
#define UNITS   256
#define G3      768
#define MROWS   4
#define NWGS    256
#define HP8     288   // A row stride in BYTES (i8); 72 dw == 8 mod 32 -> 2-way free
#define XROW    (T_STEPS * 32)   // 11,680 shorts per batch row
#define XPAD    96               // covers window-91 overread (steps 365..367)
#define WP8_BYTES (256 * G3)     // 196,608: i8 W_hh residual frags

__device__ __forceinline__ unsigned short f2bf(float x) {
    union { float f; unsigned u; } v; v.f = x;
    return (unsigned short)((v.u + 0x7FFFu + ((v.u >> 16) & 1u)) >> 16);
}
__device__ __forceinline__ float rcp_(float x) {
    float r; asm("v_rcp_f32 %0, %1" : "=v"(r) : "v"(x)); return r;
}
__device__ __forceinline__ float sigm_(float x) {      // rcp(1+e^-x); rcp(inf)=0
    return rcp_(1.0f + __expf(-x));
}
__device__ __forceinline__ float tanh_(float x) {      // 1-2*rcp(1+e^2x)
    return 1.0f - 2.0f * rcp_(1.0f + __expf(2.0f * x));
}
__device__ __forceinline__ f32x4 MF(short8 a, short8 b, f32x4 c) {
    return __builtin_amdgcn_mfma_f32_16x16x32_bf16(a, b, c, 0, 0, 0);
}
__device__ __forceinline__ i32x4 MI(i32x4 a, i32x4 b, i32x4 c) {
    return __builtin_amdgcn_mfma_i32_16x16x64_i8(a, b, c, 0, 0, 0);
}

// Pack weights (identical to R12..R16, validated):
//  - W_hh residual (k<256) -> i8 frags: (k,n) at wp8[((k>>6)*768+n)*64+(k&63)],
//    value rint(v*1024) clamped to +-127.
//  - W_ih -> bf16 frags: (kx,n) at wpx[((kx>>3)*768+n)*8+(kx&7)]
__global__ __launch_bounds__(256) void pack_weights(
    const float* __restrict__ w_ih, const float* __restrict__ w_hh,
    signed char* __restrict__ wp8, unsigned short* __restrict__ wpx)
{
    int idx = blockIdx.x * 256 + threadIdx.x;
    if (idx < 256 * G3) {
        const int k = idx / G3, n = idx - k * G3;
        float v = w_hh[k * G3 + n];
        if ((n & 255) == k) v -= 1.0f;   // subtract eye3 tile (identity exact in fp32)
        int q = (int)rintf(v * 1024.0f);
        q = q > 127 ? 127 : (q < -127 ? -127 : q);
        wp8[((size_t)((k >> 6) * G3) + n) * 64 + (k & 63)] = (signed char)q;
    } else if (idx < (256 + 32) * G3) {
        const int idx2 = idx - 256 * G3;
        const int kx = idx2 / G3, n = idx2 - kx * G3;
        wpx[((size_t)((kx >> 3) * G3) + n) * 8 + (kx & 7)] = f2bf(w_ih[kx * G3 + n]);
    }
}

// One timestep at window-offset E (compile-time 0..3). FC = this window's
// x-accs (element E = this step); FN = next window's accs, computed when
// DOX. W is the runtime window index (for the next-next x A-frag load).
#define STEP_BODY(E, FC, FN, DOX, LOADX, W) do {                              \
    const int p_ = (E) & 1;                                                   \
    __syncthreads();                                                          \
    const signed char* Ap_ = &A_s[p_][0][0];                                  \
    const i32x4 a0_ = *(const i32x4*)(Ap_ + abase);                           \
    const i32x4 a1_ = *(const i32x4*)(Ap_ + abase + 64);                      \
    const i32x4 a2_ = *(const i32x4*)(Ap_ + abase + 128);                     \
    const i32x4 a3_ = *(const i32x4*)(Ap_ + abase + 192);                     \
    /* h=0 chains complete first -> tail(h0) overlaps h1's matrix burst */    \
    i32x4 if0_ = MI(a0_, bwi[0][0][0], IZERO);                                \
    i32x4 io0_ = MI(a0_, bwi[0][1][0], IZERO);                                \
    i32x4 ig0_ = MI(a0_, bwi[0][2][0], IZERO);                                \
    if0_ = MI(a1_, bwi[1][0][0], if0_);                                       \
    io0_ = MI(a1_, bwi[1][1][0], io0_);                                       \
    ig0_ = MI(a1_, bwi[1][2][0], ig0_);                                       \
    if0_ = MI(a2_, bwi[2][0][0], if0_);                                       \
    io0_ = MI(a2_, bwi[2][1][0], io0_);                                       \
    ig0_ = MI(a2_, bwi[2][2][0], ig0_);                                       \
    if0_ = MI(a3_, bwi[3][0][0], if0_);                                       \
    io0_ = MI(a3_, bwi[3][1][0], io0_);                                       \
    ig0_ = MI(a3_, bwi[3][2][0], ig0_);                                       \
    i32x4 if1_ = MI(a0_, bwi[0][0][1], IZERO);                                \
    i32x4 io1_ = MI(a0_, bwi[0][1][1], IZERO);                                \
    i32x4 ig1_ = MI(a0_, bwi[0][2][1], IZERO);                                \
    if1_ = MI(a1_, bwi[1][0][1], if1_);                                       \
    io1_ = MI(a1_, bwi[1][1][1], io1_);                                       \
    ig1_ = MI(a1_, bwi[1][2][1], ig1_);                                       \
    if1_ = MI(a2_, bwi[2][0][1], if1_);                                       \
    io1_ = MI(a2_, bwi[2][1][1], io1_);                                       \
    ig1_ = MI(a2_, bwi[2][2][1], ig1_);                                       \
    if1_ = MI(a3_, bwi[3][0][1], if1_);                                       \
    io1_ = MI(a3_, bwi[3][1][1], io1_);                                       \
    ig1_ = MI(a3_, bwi[3][2][1], ig1_);                                       \
    if (DOX) {                                                                \
        /* next window's x-GEMM: 4 timesteps in M-dim, fills matrix pipe */   \
        const short8 xu_ = xa;                                                \
        FN[0] = MF(xu_, bwx[0][0], FZERO);                                    \
        FN[1] = MF(xu_, bwx[1][0], FZERO);                                    \
        FN[2] = MF(xu_, bwx[2][0], FZERO);                                    \
        FN[3] = MF(xu_, bwx[0][1], FZERO);                                    \
        FN[4] = MF(xu_, bwx[1][1], FZERO);                                    \
        FN[5] = MF(xu_, bwx[2][1], FZERO);                                    \
        if (LOADX)                                                            \
            xa = *(const short8*)(xq + (size_t)((W) + 2) * 128);              \
    }                                                                         \
    {   /* tail h=0: x-part element E, i8-part element 0 (duplicated) */      \
        const float bh_ = hp[0];                                              \
        const float gf_ = FC[0][E] + bfv[0] + bh_ + (float)if0_[0] * SCL;     \
        const float go_ = FC[1][E] + bov[0] + bh_ + (float)io0_[0] * SCL;     \
        const float gg_ = FC[2][E] + bgv[0] + bh_ + (float)ig0_[0] * SCL;     \
        const float f_  = sigm_(gf_);                                         \
        const float o_  = sigm_(go_);                                         \
        const float gt_ = tanh_(gg_);                                         \
        const float cn_ = f_ * cc[0] + ig[0] * gt_;                           \
        cc[0] = cn_;                                                          \
        const float hn_ = o_ * tanh_(cn_);                                    \
        hp[0] = hn_;                                                          \
        A_s[p_ ^ 1][qq][u0] = (signed char)__float2int_rn(hn_ * 127.0f);      \
    }                                                                         \
    {   /* tail h=1 */                                                        \
        const float bh_ = hp[1];                                              \
        const float gf_ = FC[3][E] + bfv[1] + bh_ + (float)if1_[0] * SCL;     \
        const float go_ = FC[4][E] + bov[1] + bh_ + (float)io1_[0] * SCL;     \
        const float gg_ = FC[5][E] + bgv[1] + bh_ + (float)ig1_[0] * SCL;     \
        const float f_  = sigm_(gf_);                                         \
        const float o_  = sigm_(go_);                                         \
        const float gt_ = tanh_(gg_);                                         \
        const float cn_ = f_ * cc[1] + ig[1] * gt_;                           \
        cc[1] = cn_;                                                          \
        const float hn_ = o_ * tanh_(cn_);                                    \
        hp[1] = hn_;                                                          \
        A_s[p_ ^ 1][qq][u1] = (signed char)__float2int_rn(hn_ * 127.0f);      \
    }                                                                         \
} while (0)

// 4-step window W: steps 4W..4W+3, x-accs FC; xstep (E=1) computes FN.
#define WINDOW4(W, FC, FN, LOADX) do {                                        \
    STEP_BODY(0, FC, FN, false, false, W);                                    \
    STEP_BODY(1, FC, FN, true,  LOADX, W);                                    \
    STEP_BODY(2, FC, FN, false, false, W);                                    \
    STEP_BODY(3, FC, FN, false, false, W);                                    \
} while (0)

__global__ __launch_bounds__(512, 2) void lstm_mfma(
    const float* __restrict__ x_dyn,   // [1024][365][32]
    const float* __restrict__ x_sta,   // [1024][27]
    const signed char* __restrict__ wp8,    // i8 W_hh residual frags
    const unsigned short* __restrict__ wpx, // bf16 W_ih frags
    const float* __restrict__ w_sh,    // [27][256]
    const float* __restrict__ bias,    // [768]
    const float* __restrict__ bias_s,  // [256]
    float* __restrict__ out)           // [1024][256]
{
    __shared__ signed char A_s[2][MROWS][HP8];        // 2,304 B (h as i8, dbuf)
    __shared__ unsigned short xs[MROWS * XROW + XPAD]; // 93,632 B (all x, bf16)

    const int tid  = threadIdx.x;
    const int b0   = blockIdx.x * MROWS;
    const int lane = tid & 63;
    const int wv   = tid >> 6;          // wave 0..7, owns units wv*32..+31
    const int mm   = lane & 15;
    const int qq   = lane >> 4;

    // ---- W_hh residual frags resident: 4 ks x 3 gates x 2 halves = 96 regs ----
    i32x4 bwi[4][3][2];
    #pragma unroll
    for (int ks = 0; ks < 4; ++ks)
        #pragma unroll
        for (int g = 0; g < 3; ++g)
            #pragma unroll
            for (int h = 0; h < 2; ++h) {
                const int n = g * UNITS + wv * 32 + h * 16 + mm;
                bwi[ks][g][h] = *(const i32x4*)(wp8 +
                    ((size_t)(ks * G3) + n) * 64 + qq * 16);
            }
    short8 bwx[3][2];
    #pragma unroll
    for (int g = 0; g < 3; ++g)
        #pragma unroll
        for (int h = 0; h < 2; ++h)
            bwx[g][h] = *(const short8*)(wpx +
                ((size_t)(qq * G3) + g * UNITS + wv * 32 + h * 16 + mm) * 8);

    // ---- pre-stage ALL x for this WG's 4 batch rows (fp32 -> bf16) ----
    #pragma unroll
    for (int r = 0; r < MROWS; ++r) {
        const float4* src = (const float4*)(x_dyn + (size_t)(b0 + r) * XROW);
        short4s* dst = (short4s*)(xs + r * XROW);
        for (int i = tid; i < XROW / 4; i += 512) {
            const float4 v = src[i];
            short4s w;
            w.x = (short)f2bf(v.x); w.y = (short)f2bf(v.y);
            w.z = (short)f2bf(v.z); w.w = (short)f2bf(v.w);
            dst[i] = w;
        }
    }
    // zero the pad (window-91 overread) and both h buffers
    if (tid < XPAD / 2) ((int*)(xs + MROWS * XROW))[tid] = 0;
    {
        int* az = (int*)A_s;
        for (int i = tid; i < 2 * MROWS * HP8 / 4; i += 512) az[i] = 0;
    }
    __syncthreads();

    // ---- cell mapping: lane (mm,qq) owns cells (batch row qq, units u0,u1).
    //      h A-rows GROUPED (arow = mm>>2): i8 acc elements all identical.
    //      x A-rows = (batch mm>>2, t0 + (mm&3)): acc element e = timestep. ----
    const int u0 = wv * 32 + mm;
    const int u1 = u0 + 16;

    const float bfv[2] = { bias[u0],             bias[u1] };
    const float bov[2] = { bias[UNITS + u0],     bias[UNITS + u1] };
    const float bgv[2] = { bias[2 * UNITS + u0], bias[2 * UNITS + u1] };

    float ig[2], cc[2], hp[2];
    #pragma unroll
    for (int h = 0; h < 2; ++h) {
        const int u = h ? u1 : u0;
        float s = bias_s[u];
        #pragma unroll
        for (int j = 0; j < 27; ++j)
            s += x_sta[(b0 + qq) * 27 + j] * w_sh[j * UNITS + u];
        ig[h] = sigm_(s);
        cc[h] = 0.0f; hp[h] = 0.0f;
    }

    const int abase = (mm >> 2) * HP8 + qq * 16;        // grouped h A-read
    // x A-frag source: row (batch mm>>2, timestep t0+(mm&3)), k-slice qq*8
    const unsigned short* xq = xs + (size_t)(mm >> 2) * XROW + (mm & 3) * 32 + qq * 8;
    const float SCL = 1.0f / (127.0f * 1024.0f);
    const f32x4 FZERO = {0.f, 0.f, 0.f, 0.f};
    const i32x4 IZERO = {0, 0, 0, 0};

    // ---- prologue: window 0 accs into FA; prefetch window-1 x A-frag ----
    f32x4 FA[6], FB[6];
    short8 xa;
    {
        const short8 x0 = *(const short8*)(xq);
        FA[0] = MF(x0, bwx[0][0], FZERO);
        FA[1] = MF(x0, bwx[1][0], FZERO);
        FA[2] = MF(x0, bwx[2][0], FZERO);
        FA[3] = MF(x0, bwx[0][1], FZERO);
        FA[4] = MF(x0, bwx[1][1], FZERO);
        FA[5] = MF(x0, bwx[2][1], FZERO);
        xa = *(const short8*)(xq + 128);   // window 1
    }

    // windows 0..89 in ping-pong pairs, window 90, then final step 364
    for (int wp = 0; wp < 45; ++wp) {
        const int w0 = wp * 2;
        WINDOW4(w0,     FA, FB, true);
        WINDOW4(w0 + 1, FB, FA, true);
    }
    WINDOW4(90, FA, FB, false);            // computes FB for window 91 (step 364)
    STEP_BODY(0, FB, FA, false, false, 91);

    out[(size_t)(b0 + qq) * UNITS + u0] = hp[0];
    out[(size_t)(b0 + qq) * UNITS + u1] = hp[1];
}

extern "C" void kernel_launch(void* const* d_in, const int* in_sizes, int n_in,
                              void* d_out, int out_size, void* d_ws, size_t ws_size,
                              hipStream_t stream) {
    const float* x_dyn  = (const float*)d_in[0];
    const float* x_sta  = (const float*)d_in[1];
    const float* w_ih   = (const float*)d_in[2];
    const float* w_hh   = (const float*)d_in[3];
    const float* w_sh   = (const float*)d_in[4];
    const float* bias   = (const float*)d_in[5];
    const float* bias_s = (const float*)d_in[6];
    float* out = (float*)d_out;
    signed char* wp8 = (signed char*)d_ws;                            // 196,608 B
    unsigned short* wpx = (unsigned short*)((char*)d_ws + WP8_BYTES); //  49,152 B

    pack_weights<<<((256 + 32) * G3 + 255) / 256, 256, 0, stream>>>(w_ih, w_hh, wp8, wpx);
    lstm_mfma<<<NWGS, 512, 0, stream>>>(x_dyn, x_sta, wp8, wpx, w_sh, bias, bias_s, out);
}